// Round 8
// baseline (599.974 us; speedup 1.0000x reference)
//
#include <hip/hip_runtime.h>
#include <math.h>

#define Bn 4
#define Ln 1024
#define Dn 128
#define Hn 8
#define Gn 64
#define NITERS 4

typedef _Float16 f16;
typedef _Float16 half8 __attribute__((ext_vector_type(8)));
typedef _Float16 half4v __attribute__((ext_vector_type(4)));
typedef float floatx4 __attribute__((ext_vector_type(4)));

#define PPAD 72    // f16 stride, P tile [i][j] / [j][i]

#define MFMA(a, b, c) __builtin_amdgcn_mfma_f32_16x16x32_f16((a), (b), (c), 0, 0, 0)

// async global->LDS, 16B per lane; dest = lds_base + lane*16 (wave-uniform base)
__device__ __forceinline__ void gl_lds16(const f16* g, f16* l) {
    __builtin_amdgcn_global_load_lds(
        (const __attribute__((address_space(1))) void*)(g),
        (__attribute__((address_space(3))) void*)(l),
        16, 0, 0);
}

// Issue a 128x64 tile (row stride sb) into UbB, XOR-swizzled: 16B-group g
// stored at g^(row&7). Inverse swizzle applied to the global address.
__device__ __forceinline__ void issue_ub(const f16* ub, int sb, f16* UbB, int w, int l) {
    #pragma unroll
    for (int k = 0; k < 4; k++) {
        int c = w * 4 + k;
        int r = c * 8 + (l >> 3); int g = (l & 7) ^ (r & 7);
        gl_lds16(ub + (size_t)r * sb + g * 8, UbB + c * 512);
    }
}

// ---------------- repack ternary/global into f16 per-head layouts -----------
__global__ void repack_kernel(const float* __restrict__ ter, const float* __restrict__ glb,
                              f16* __restrict__ TpA, f16* __restrict__ TpB,
                              f16* __restrict__ GpA, f16* __restrict__ Gpt) {
    int idx = blockIdx.x * 256 + threadIdx.x;
    if (idx < Dn * Dn * Hn) {
        int h = idx % Hn; int b = (idx / Hn) % Dn; int a = idx / (Hn * Dn);
        f16 v = (f16)ter[idx];
        TpA[((size_t)h * Dn + a) * Dn + b] = v;
        TpB[((size_t)h * Dn + b) * Dn + a] = v;
    }
    if (idx < Gn * Dn * Hn) {
        int h = idx % Hn; int a = (idx / Hn) % Dn; int g = idx / (Hn * Dn);
        f16 v = (f16)glb[idx];
        GpA[((size_t)h * Gn + g) * Dn + a] = v;
        Gpt[((size_t)h * Dn + a) * Gn + g] = v;
    }
}

// ---------------- row softmax over D=128 (fp32 in, f16 out) -----------------
__global__ void softmax_rows_kernel(const float* __restrict__ in, f16* __restrict__ out) {
    int row = blockIdx.x;
    int t = threadIdx.x;  // 0..127
    __shared__ float red[2];
    float v = in[(size_t)row * Dn + t];
    float m = v;
    #pragma unroll
    for (int off = 1; off < 64; off <<= 1) m = fmaxf(m, __shfl_xor(m, off, 64));
    if ((t & 63) == 0) red[t >> 6] = m;
    __syncthreads();
    m = fmaxf(red[0], red[1]);
    float e = __expf(v - m);
    float s = e;
    #pragma unroll
    for (int off = 1; off < 64; off <<= 1) s += __shfl_xor(s, off, 64);
    __syncthreads();
    if ((t & 63) == 0) red[t >> 6] = s;
    __syncthreads();
    s = red[0] + red[1];
    out[(size_t)row * Dn + t] = (f16)(e / s);
}

// ---------------- U/V projection via MFMA, fully LDS-free -------------------
// B-fragments read directly from global T (L2-resident, 512 KB total).
__launch_bounds__(256, 4)
__global__ void uv_kernel(const f16* __restrict__ Qz, const f16* __restrict__ TpA,
                          const f16* __restrict__ TpB,
                          f16* __restrict__ U, f16* __restrict__ Ut, f16* __restrict__ Vt) {
    int bx = blockIdx.x;  // 16 j-strips of 64
    int h  = blockIdx.y;
    int n  = blockIdx.z;
    int t  = threadIdx.x;
    int w = t >> 6, l = t & 63, m = l & 15, q = l >> 4;

    int jrow = bx * 64 + w * 16 + m;
    const f16* qbase = Qz + ((size_t)n * Ln + jrow) * Dn;
    half8 aq[4];
    #pragma unroll
    for (int ks = 0; ks < 4; ks++)
        aq[ks] = *(const half8*)(qbase + ks * 32 + q * 8);

    size_t hoff = (size_t)(n * Hn + h);
    int jr0 = bx * 64 + w * 16 + 4 * q;

    // ---- pass 1: U = Qz * TpA^T ----
    {
        const f16* src = TpA + (size_t)h * Dn * Dn;
        #pragma unroll
        for (int ct = 0; ct < 8; ct++) {
            floatx4 acc = {0.f, 0.f, 0.f, 0.f};
            #pragma unroll
            for (int ks = 0; ks < 4; ks++) {
                half8 b = *(const half8*)(src + (size_t)(ct * 16 + m) * Dn + ks * 32 + q * 8);
                acc = MFMA(aq[ks], b, acc);
            }
            f16* ub = U + (hoff * Ln + jr0) * Dn + ct * 16 + m;
            #pragma unroll
            for (int reg = 0; reg < 4; reg++) ub[(size_t)reg * Dn] = (f16)acc[reg];
            half4v pk = { (f16)acc[0], (f16)acc[1], (f16)acc[2], (f16)acc[3] };
            *(half4v*)(Ut + (hoff * Dn + ct * 16 + m) * Ln + jr0) = pk;
        }
    }
    // ---- pass 2: V = Qz * TpB^T, stored transposed ----
    {
        const f16* src = TpB + (size_t)h * Dn * Dn;
        #pragma unroll
        for (int ct = 0; ct < 8; ct++) {
            floatx4 acc = {0.f, 0.f, 0.f, 0.f};
            #pragma unroll
            for (int ks = 0; ks < 4; ks++) {
                half8 b = *(const half8*)(src + (size_t)(ct * 16 + m) * Dn + ks * 32 + q * 8);
                acc = MFMA(aq[ks], b, acc);
            }
            half4v pk = { (f16)acc[0], (f16)acc[1], (f16)acc[2], (f16)acc[3] };
            *(half4v*)(Vt + (hoff * Dn + ct * 16 + m) * Ln + jr0) = pk;
        }
    }
}

// ---------------- msg_i + msg_g: global score A-frags + DMA'd PV B-tiles ----
// Scores S^T (A = U j-rows read DIRECT FROM GLOBAL (L2/L1-hit), B = resident
// Qz i-rows). PV B-operand (Ut slice) staged via async DMA double-buffer.
__launch_bounds__(256, 2)
__global__ void msgi_kernel(const f16* __restrict__ Qz, const f16* __restrict__ U,
                            const f16* __restrict__ Ut, const f16* __restrict__ GpA,
                            const f16* __restrict__ Gpt, const int* __restrict__ mask,
                            f16* __restrict__ Macc, float* __restrict__ rowLinv) {
    int it = blockIdx.x, h = blockIdx.y, n = blockIdx.z;
    int t = threadIdx.x;
    int w = t >> 6, l = t & 63, m = l & 15, q = l >> 4;
    int rh = w >> 1, ch = w & 1;   // scores: j-half (rows), i-half (cols)
    int ih = w >> 1, ah = w & 1;   // PV: i-half (rows), a-half (cols)

    __shared__ __align__(16) f16 Ub[2][128 * 64];    // Ut slice [a][j], swizzled
    __shared__ __align__(16) f16 Ps[64 * PPAD];      // P[i][j], padded
    __shared__ float lpart[2][64];
    __shared__ float linvS[64];

    // resident B-frags: Qz rows of this i-tile (jt-invariant, 32 VGPRs)
    half8 bq[2][4];
    #pragma unroll
    for (int ib = 0; ib < 2; ib++) {
        const f16* qr = Qz + ((size_t)n * Ln + it * 64 + ch * 32 + ib * 16 + m) * Dn;
        #pragma unroll
        for (int ks = 0; ks < 4; ks++)
            bq[ib][ks] = *(const half8*)(qr + ks * 32 + q * 8);
    }
    int im[2];
    #pragma unroll
    for (int ib = 0; ib < 2; ib++)
        im[ib] = mask[n * Ln + it * 64 + ch * 32 + ib * 16 + m];

    float lacc[2] = {0.f, 0.f};
    floatx4 Oacc[2][4];
    #pragma unroll
    for (int ib = 0; ib < 2; ib++)
        #pragma unroll
        for (int at = 0; at < 4; at++) Oacc[ib][at] = (floatx4){0.f, 0.f, 0.f, 0.f};

    size_t hoff = (size_t)(n * Hn + h);

    // preload jt=0 PV tile
    issue_ub(Ut + hoff * Dn * Ln, Ln, Ub[0], w, l);
    __syncthreads();  // drains DMA (vmcnt0 at barrier)

    for (int jt = 0; jt < 17; jt++) {
        int cur = jt & 1, nxt = cur ^ 1;
        // issue next PV tile into the free buffer
        if (jt + 1 < 17) {
            const f16* ub; int sb;
            if (jt + 1 < 16) { ub = Ut + hoff * Dn * Ln + (jt + 1) * 64; sb = Ln; }
            else             { ub = Gpt + (size_t)h * Dn * Gn;           sb = Gn; }
            issue_ub(ub, sb, Ub[nxt], w, l);
        }
        int isg = (jt == 16);
        const f16* uptr = isg ? (GpA + (size_t)h * Gn * Dn)
                              : (U + (hoff * Ln + (size_t)jt * 64) * Dn);
        // scores S^T[j][i]: A-frags direct from global (L2-hit); write P[i][j]
        #pragma unroll
        for (int jb = 0; jb < 2; jb++) {
            int r0 = rh * 32 + jb * 16 + m;
            half8 au[4];
            #pragma unroll
            for (int ks = 0; ks < 4; ks++)
                au[ks] = *(const half8*)(uptr + (size_t)r0 * Dn + ks * 32 + q * 8);
            int4 jmv;
            if (isg) jmv = make_int4(1, 1, 1, 1);
            else jmv = *(const int4*)(mask + n * Ln + jt * 64 + rh * 32 + jb * 16 + 4 * q);
            const int* jmr = &jmv.x;
            #pragma unroll
            for (int ib = 0; ib < 2; ib++) {
                floatx4 s = {0.f, 0.f, 0.f, 0.f};
                #pragma unroll
                for (int ks = 0; ks < 4; ks++) s = MFMA(au[ks], bq[ib][ks], s);
                half4v pk;
                #pragma unroll
                for (int reg = 0; reg < 4; reg++) {
                    float p = (isg || (im[ib] && jmr[reg])) ? __expf(fminf(s[reg], 11.f)) : 0.f;
                    lacc[ib] += p;
                    pk[reg] = (f16)p;
                }
                *(half4v*)&Ps[(ch * 32 + ib * 16 + m) * PPAD + rh * 32 + jb * 16 + 4 * q] = pk;
            }
        }
        __syncthreads();  // P visible (also drains jt+1 DMA)

        // PV: O[i][a] += P[i][j] * U[j][a]; B-frags from swizzled Ub[cur]
        #pragma unroll
        for (int kst = 0; kst < 2; kst++) {
            half8 aP[2];
            #pragma unroll
            for (int ib = 0; ib < 2; ib++)
                aP[ib] = *(const half8*)&Ps[(ih * 32 + ib * 16 + m) * PPAD + kst * 32 + q * 8];
            #pragma unroll
            for (int at = 0; at < 4; at++) {
                int r0 = ah * 64 + at * 16 + m;
                half8 bU = *(const half8*)&Ub[cur][((size_t)r0 << 6) + ((((kst << 2) + q)) ^ (r0 & 7)) * 8];
                #pragma unroll
                for (int ib = 0; ib < 2; ib++)
                    Oacc[ib][at] = MFMA(aP[ib], bU, Oacc[ib][at]);
            }
        }
        __syncthreads();  // release Ps + Ub[cur] for jt+2 DMA
    }

    // epilogue: row sums (cols i live on m-lanes; sum over q then across rh)
    #pragma unroll
    for (int ib = 0; ib < 2; ib++) {
        float v = lacc[ib];
        v += __shfl_xor(v, 16, 64);
        v += __shfl_xor(v, 32, 64);
        lacc[ib] = v;
    }
    if (q == 0) {
        lpart[rh][ch * 32 + m] = lacc[0];
        lpart[rh][ch * 32 + 16 + m] = lacc[1];
    }
    __syncthreads();
    size_t rbase = hoff * Ln + (size_t)it * 64;
    if (t < 64) {
        float inv = 1.0f / (lpart[0][t] + lpart[1][t]);
        linvS[t] = inv;
        int mk = mask[n * Ln + it * 64 + t];
        rowLinv[rbase + t] = mk ? inv : 0.f;  // i-mask folded for msgj
    }
    __syncthreads();
    f16* Mo = Macc + rbase * Dn;
    #pragma unroll
    for (int ib = 0; ib < 2; ib++)
        #pragma unroll
        for (int reg = 0; reg < 4; reg++) {
            int row = ih * 32 + ib * 16 + 4 * q + reg;
            float inv = linvS[row];
            #pragma unroll
            for (int at = 0; at < 4; at++)
                Mo[(size_t)row * Dn + ah * 64 + at * 16 + m] = (f16)(Oacc[ib][at][reg] * inv);
        }
}

// ---------------- msg_j: mirrored — global Qz A-frags + DMA'd Vt tiles ------
__launch_bounds__(256, 2)
__global__ void msgj_kernel(const f16* __restrict__ Qz, const f16* __restrict__ U,
                            const f16* __restrict__ Vt, const int* __restrict__ mask,
                            const float* __restrict__ rowLinv, f16* __restrict__ Macc) {
    int jt = blockIdx.x, h = blockIdx.y, n = blockIdx.z;
    int t = threadIdx.x;
    int w = t >> 6, l = t & 63, m = l & 15, q = l >> 4;
    int ihs = w >> 1, jhs = w & 1;  // scores: i-half (rows), j-half (cols)
    int jh2 = w >> 1, bh = w & 1;   // PV: j-half (rows), b-half (cols)

    __shared__ __align__(16) f16 Vb[2][128 * 64];   // Vt slice [b][i], swizzled
    __shared__ __align__(16) f16 Psj[64 * PPAD];    // P'[j][i], padded

    size_t hoff = (size_t)(n * Hn + h);

    // resident B-frags: U rows of this j-tile (it2-invariant)
    half8 bu[2][4];
    #pragma unroll
    for (int jb = 0; jb < 2; jb++) {
        const f16* ur = U + (hoff * Ln + (size_t)jt * 64 + jhs * 32 + jb * 16 + m) * Dn;
        #pragma unroll
        for (int ks = 0; ks < 4; ks++)
            bu[jb][ks] = *(const half8*)(ur + ks * 32 + q * 8);
    }
    int jm[2];
    #pragma unroll
    for (int jb = 0; jb < 2; jb++)
        jm[jb] = mask[n * Ln + jt * 64 + jhs * 32 + jb * 16 + m];

    floatx4 Oacc[2][4];
    #pragma unroll
    for (int jb = 0; jb < 2; jb++)
        #pragma unroll
        for (int bt = 0; bt < 4; bt++) Oacc[jb][bt] = (floatx4){0.f, 0.f, 0.f, 0.f};

    // preload it2=0 PV tile
    issue_ub(Vt + hoff * Dn * Ln, Ln, Vb[0], w, l);
    __syncthreads();

    for (int it2 = 0; it2 < 16; it2++) {
        int cur = it2 & 1, nxt = cur ^ 1;
        if (it2 + 1 < 16)
            issue_ub(Vt + hoff * Dn * Ln + (it2 + 1) * 64, Ln, Vb[nxt], w, l);
        const f16* qptr = Qz + ((size_t)n * Ln + (size_t)it2 * 64) * Dn;
        // scores S[i][j]: A-frags direct from global; write P'[j][i]
        #pragma unroll
        for (int ib = 0; ib < 2; ib++) {
            int r0 = ihs * 32 + ib * 16 + m;
            half8 aq2[4];
            #pragma unroll
            for (int ks = 0; ks < 4; ks++)
                aq2[ks] = *(const half8*)(qptr + (size_t)r0 * Dn + ks * 32 + q * 8);
            float4 lvv = *(const float4*)(rowLinv + hoff * Ln + it2 * 64 + ihs * 32 + ib * 16 + 4 * q);
            const float* lv = &lvv.x;
            #pragma unroll
            for (int jb = 0; jb < 2; jb++) {
                floatx4 s = {0.f, 0.f, 0.f, 0.f};
                #pragma unroll
                for (int ks = 0; ks < 4; ks++) s = MFMA(aq2[ks], bu[jb][ks], s);
                half4v pk;
                #pragma unroll
                for (int reg = 0; reg < 4; reg++) {
                    float p = jm[jb] ? __expf(fminf(s[reg], 11.f)) * lv[reg] : 0.f;
                    pk[reg] = (f16)p;
                }
                *(half4v*)&Psj[(jhs * 32 + jb * 16 + m) * PPAD + ihs * 32 + ib * 16 + 4 * q] = pk;
            }
        }
        __syncthreads();  // P' visible (drains next DMA too)

        // PV: O[j][b] += P'[j][i] * V[i][b]
        #pragma unroll
        for (int kst = 0; kst < 2; kst++) {
            half8 aP[2];
            #pragma unroll
            for (int jb = 0; jb < 2; jb++)
                aP[jb] = *(const half8*)&Psj[(jh2 * 32 + jb * 16 + m) * PPAD + kst * 32 + q * 8];
            #pragma unroll
            for (int bt = 0; bt < 4; bt++) {
                int r0 = bh * 64 + bt * 16 + m;
                half8 bV = *(const half8*)&Vb[cur][((size_t)r0 << 6) + ((((kst << 2) + q)) ^ (r0 & 7)) * 8];
                #pragma unroll
                for (int jb = 0; jb < 2; jb++)
                    Oacc[jb][bt] = MFMA(aP[jb], bV, Oacc[jb][bt]);
            }
        }
        __syncthreads();  // release Psj + Vb[cur]
    }

    f16* Mo = Macc + (hoff * Ln + (size_t)jt * 64) * Dn;
    #pragma unroll
    for (int jb = 0; jb < 2; jb++)
        #pragma unroll
        for (int reg = 0; reg < 4; reg++) {
            int row = jh2 * 32 + jb * 16 + 4 * q + reg;
            #pragma unroll
            for (int bt = 0; bt < 4; bt++) {
                f16* p = &Mo[(size_t)row * Dn + bh * 64 + bt * 16 + m];
                *p = (f16)((float)*p + Oacc[jb][bt][reg]);
            }
        }
}

// ---------------- fused combine (+softmax | +mask) --------------------------
__global__ void combine_kernel(const float* __restrict__ x, const f16* __restrict__ Macc,
                               const int* __restrict__ mask, float* __restrict__ out,
                               f16* __restrict__ Qzh, int do_softmax, int do_mask) {
    int row = blockIdx.x;           // B*L rows
    int t = threadIdx.x;            // 0..127
    __shared__ float red[2];
    int n = row >> 10;
    float acc = x[(size_t)row * Dn + t];
    const f16* mp = Macc + (size_t)n * Hn * Ln * Dn + (size_t)(row & 1023) * Dn + t;
    #pragma unroll
    for (int h = 0; h < Hn; h++) acc += (float)mp[(size_t)h * Ln * Dn];
    float o = acc;
    if (do_mask && mask[row] == 0) o = 0.f;
    out[(size_t)row * Dn + t] = o;
    if (do_softmax) {
        float m = acc;
        #pragma unroll
        for (int off = 1; off < 64; off <<= 1) m = fmaxf(m, __shfl_xor(m, off, 64));
        if ((t & 63) == 0) red[t >> 6] = m;
        __syncthreads();
        m = fmaxf(red[0], red[1]);
        float e = __expf(acc - m);
        float s = e;
        #pragma unroll
        for (int off = 1; off < 64; off <<= 1) s += __shfl_xor(s, off, 64);
        __syncthreads();
        if ((t & 63) == 0) red[t >> 6] = s;
        __syncthreads();
        s = red[0] + red[1];
        Qzh[(size_t)row * Dn + t] = (f16)(e / s);
    }
}

extern "C" void kernel_launch(void* const* d_in, const int* in_sizes, int n_in,
                              void* d_out, int out_size, void* d_ws, size_t ws_size,
                              hipStream_t stream) {
    const float* x       = (const float*)d_in[0];
    const int*   mask    = (const int*)d_in[1];
    const float* ternary = (const float*)d_in[2];
    const float* global_ = (const float*)d_in[3];
    float* out = (float*)d_out;
    (void)ws_size; (void)n_in; (void)in_sizes; (void)out_size;

    char* ws = (char*)d_ws;
    size_t o = 0;
    f16* Qzh = (f16*)(ws + o); o += (size_t)Bn * Ln * Dn * 2;
    f16* U   = (f16*)(ws + o); o += (size_t)Bn * Hn * Ln * Dn * 2;
    f16* Ut  = (f16*)(ws + o); o += (size_t)Bn * Hn * Ln * Dn * 2;
    f16* Vt  = (f16*)(ws + o); o += (size_t)Bn * Hn * Ln * Dn * 2;
    f16* TpA = (f16*)(ws + o); o += (size_t)Hn * Dn * Dn * 2;
    f16* TpB = (f16*)(ws + o); o += (size_t)Hn * Dn * Dn * 2;
    f16* GpA = (f16*)(ws + o); o += (size_t)Hn * Gn * Dn * 2;
    f16* Gpt = (f16*)(ws + o); o += (size_t)Hn * Dn * Gn * 2;
    float* rowLinv = (float*)(ws + o); o += (size_t)Bn * Hn * Ln * 4;
    f16* Macc = (f16*)(ws + o); o += (size_t)Bn * Hn * Ln * Dn * 2;

    repack_kernel<<<(Dn * Dn * Hn + 255) / 256, 256, 0, stream>>>(ternary, global_, TpA, TpB, GpA, Gpt);
    softmax_rows_kernel<<<Bn * Ln, 128, 0, stream>>>(x, Qzh);

    for (int it = 0; it < NITERS; it++) {
        uv_kernel<<<dim3(Ln / 64, Hn, Bn), 256, 0, stream>>>(Qzh, TpA, TpB, U, Ut, Vt);
        msgi_kernel<<<dim3(Ln / 64, Hn, Bn), 256, 0, stream>>>(Qzh, U, Ut, GpA, Gpt, mask, Macc, rowLinv);
        msgj_kernel<<<dim3(Ln / 64, Hn, Bn), 256, 0, stream>>>(Qzh, U, Vt, mask, rowLinv, Macc);
        combine_kernel<<<Bn * Ln, 128, 0, stream>>>(x, Macc, mask, out, Qzh,
                                                    (it < NITERS - 1) ? 1 : 0,
                                                    (it == NITERS - 1) ? 1 : 0);
    }
}

// Round 9
// 462.909 us; speedup vs baseline: 1.2961x; 1.2961x over previous
//
#include <hip/hip_runtime.h>
#include <math.h>

#define Bn 4
#define Ln 1024
#define Dn 128
#define Hn 8
#define Gn 64
#define NITERS 4

typedef _Float16 f16;
typedef _Float16 half8 __attribute__((ext_vector_type(8)));
typedef _Float16 half4v __attribute__((ext_vector_type(4)));
typedef float floatx4 __attribute__((ext_vector_type(4)));

#define PPAD 72    // f16 stride, P tile [i][j] / [j][i]

#define MFMA(a, b, c) __builtin_amdgcn_mfma_f32_16x16x32_f16((a), (b), (c), 0, 0, 0)

// async global->LDS, 16B per lane; dest = lds_base + lane*16 (wave-uniform base)
__device__ __forceinline__ void gl_lds16(const f16* g, f16* l) {
    __builtin_amdgcn_global_load_lds(
        (const __attribute__((address_space(1))) void*)(g),
        (__attribute__((address_space(3))) void*)(l),
        16, 0, 0);
}

// Issue one 64x128 tile (row stride Dn) into UsB and one 128x64 tile (row
// stride sb) into UbB, both XOR-swizzled: 16B-group g stored at g^(row&7).
__device__ __forceinline__ void issue_tiles(const f16* us, const f16* ub, int sb,
                                            f16* UsB, f16* UbB, int w, int l) {
    #pragma unroll
    for (int k = 0; k < 4; k++) {
        int c = w * 4 + k;
        {   // Us: 64 rows x 16 groups
            int r = c * 4 + (l >> 4); int g = (l & 15) ^ (r & 7);
            gl_lds16(us + (size_t)r * Dn + g * 8, UsB + c * 512);
        }
        {   // Ub: 128 rows x 8 groups
            int r = c * 8 + (l >> 3); int g = (l & 7) ^ (r & 7);
            gl_lds16(ub + (size_t)r * sb + g * 8, UbB + c * 512);
        }
    }
}

// ---------------- repack ternary/global into f16 per-head layouts -----------
__global__ void repack_kernel(const float* __restrict__ ter, const float* __restrict__ glb,
                              f16* __restrict__ TpA, f16* __restrict__ TpB,
                              f16* __restrict__ GpA, f16* __restrict__ Gpt) {
    int idx = blockIdx.x * 256 + threadIdx.x;
    if (idx < Dn * Dn * Hn) {
        int h = idx % Hn; int b = (idx / Hn) % Dn; int a = idx / (Hn * Dn);
        f16 v = (f16)ter[idx];
        TpA[((size_t)h * Dn + a) * Dn + b] = v;
        TpB[((size_t)h * Dn + b) * Dn + a] = v;
    }
    if (idx < Gn * Dn * Hn) {
        int h = idx % Hn; int a = (idx / Hn) % Dn; int g = idx / (Hn * Dn);
        f16 v = (f16)glb[idx];
        GpA[((size_t)h * Gn + g) * Dn + a] = v;
        Gpt[((size_t)h * Dn + a) * Gn + g] = v;
    }
}

// ---------------- row softmax over D=128 (fp32 in, f16 out) -----------------
__global__ void softmax_rows_kernel(const float* __restrict__ in, f16* __restrict__ out) {
    int row = blockIdx.x;
    int t = threadIdx.x;  // 0..127
    __shared__ float red[2];
    float v = in[(size_t)row * Dn + t];
    float m = v;
    #pragma unroll
    for (int off = 1; off < 64; off <<= 1) m = fmaxf(m, __shfl_xor(m, off, 64));
    if ((t & 63) == 0) red[t >> 6] = m;
    __syncthreads();
    m = fmaxf(red[0], red[1]);
    float e = __expf(v - m);
    float s = e;
    #pragma unroll
    for (int off = 1; off < 64; off <<= 1) s += __shfl_xor(s, off, 64);
    __syncthreads();
    if ((t & 63) == 0) red[t >> 6] = s;
    __syncthreads();
    s = red[0] + red[1];
    out[(size_t)row * Dn + t] = (f16)(e / s);
}

// ---------------- U/V projection via MFMA, LDS-free, all-packed stores ------
// Pass 1/2 (A = Qz j-rows, B = T a-rows): C has j-consecutive regs -> packed
// Ut/Vt half4v stores. Pass 3 (A = TpA a-rows, B = resident Qz as B-operand):
// C has a-consecutive regs -> packed U half4v stores (replaces 32 scalar f16
// stores per lane). Operand-role swap is layout-safe: A and B fragments share
// the same lane->element mapping (proven by msgi's MFMA(au, bq) usage).
__launch_bounds__(256, 4)
__global__ void uv_kernel(const f16* __restrict__ Qz, const f16* __restrict__ TpA,
                          const f16* __restrict__ TpB,
                          f16* __restrict__ U, f16* __restrict__ Ut, f16* __restrict__ Vt) {
    int bx = blockIdx.x;  // 16 j-strips of 64
    int h  = blockIdx.y;
    int n  = blockIdx.z;
    int t  = threadIdx.x;
    int w = t >> 6, l = t & 63, m = l & 15, q = l >> 4;

    const f16* qbase = Qz + ((size_t)n * Ln + bx * 64 + w * 16 + m) * Dn;
    half8 aq[4];
    #pragma unroll
    for (int ks = 0; ks < 4; ks++)
        aq[ks] = *(const half8*)(qbase + ks * 32 + q * 8);

    size_t hoff = (size_t)(n * Hn + h);
    int jr0 = bx * 64 + w * 16 + 4 * q;
    const f16* srcA = TpA + (size_t)h * Dn * Dn;
    const f16* srcB = TpB + (size_t)h * Dn * Dn;

    // ---- pass 1: Ut[a][j] = (Qz * TpA^T)^T, packed j-direction stores ----
    #pragma unroll
    for (int ct = 0; ct < 8; ct++) {
        floatx4 acc = {0.f, 0.f, 0.f, 0.f};
        #pragma unroll
        for (int ks = 0; ks < 4; ks++) {
            half8 b = *(const half8*)(srcA + (size_t)(ct * 16 + m) * Dn + ks * 32 + q * 8);
            acc = MFMA(aq[ks], b, acc);
        }
        half4v pk = { (f16)acc[0], (f16)acc[1], (f16)acc[2], (f16)acc[3] };
        *(half4v*)(Ut + (hoff * Dn + ct * 16 + m) * Ln + jr0) = pk;
    }
    // ---- pass 2: Vt[b][i] = (Qz * TpB^T)^T ----
    #pragma unroll
    for (int ct = 0; ct < 8; ct++) {
        floatx4 acc = {0.f, 0.f, 0.f, 0.f};
        #pragma unroll
        for (int ks = 0; ks < 4; ks++) {
            half8 b = *(const half8*)(srcB + (size_t)(ct * 16 + m) * Dn + ks * 32 + q * 8);
            acc = MFMA(aq[ks], b, acc);
        }
        half4v pk = { (f16)acc[0], (f16)acc[1], (f16)acc[2], (f16)acc[3] };
        *(half4v*)(Vt + (hoff * Dn + ct * 16 + m) * Ln + jr0) = pk;
    }
    // ---- pass 3: U[j][a] with A = T a-rows, B = aq (role swap) ----
    // out rows a = at*16+4q+reg, col j = w*16+m  -> a-consecutive packed store
    f16* urow = U + (hoff * Ln + (size_t)(bx * 64 + w * 16 + m)) * Dn;
    #pragma unroll
    for (int at = 0; at < 8; at++) {
        floatx4 acc = {0.f, 0.f, 0.f, 0.f};
        #pragma unroll
        for (int ks = 0; ks < 4; ks++) {
            half8 aT = *(const half8*)(srcA + (size_t)(at * 16 + m) * Dn + ks * 32 + q * 8);
            acc = MFMA(aT, aq[ks], acc);
        }
        half4v pk = { (f16)acc[0], (f16)acc[1], (f16)acc[2], (f16)acc[3] };
        *(half4v*)(urow + at * 16 + 4 * q) = pk;
    }
}

// ---------------- msg_i + msg_g: R7-exact (DMA double-buffer) ---------------
__launch_bounds__(256, 2)
__global__ void msgi_kernel(const f16* __restrict__ Qz, const f16* __restrict__ U,
                            const f16* __restrict__ Ut, const f16* __restrict__ GpA,
                            const f16* __restrict__ Gpt, const int* __restrict__ mask,
                            f16* __restrict__ Macc, float* __restrict__ rowLinv) {
    int it = blockIdx.x, h = blockIdx.y, n = blockIdx.z;
    int t = threadIdx.x;
    int w = t >> 6, l = t & 63, m = l & 15, q = l >> 4;
    int rh = w >> 1, ch = w & 1;   // scores: j-half (rows), i-half (cols)
    int ih = w >> 1, ah = w & 1;   // PV: i-half (rows), a-half (cols)

    __shared__ __align__(16) f16 Us[2][64 * 128];    // U j-tile, swizzled
    __shared__ __align__(16) f16 Ub[2][128 * 64];    // Ut slice [a][j], swizzled
    __shared__ __align__(16) f16 Ps[64 * PPAD];      // P[i][j], padded
    __shared__ int jms[2][64];
    __shared__ float lpart[2][64];
    __shared__ float linvS[64];

    half8 bq[2][4];
    #pragma unroll
    for (int ib = 0; ib < 2; ib++) {
        const f16* qr = Qz + ((size_t)n * Ln + it * 64 + ch * 32 + ib * 16 + m) * Dn;
        #pragma unroll
        for (int ks = 0; ks < 4; ks++)
            bq[ib][ks] = *(const half8*)(qr + ks * 32 + q * 8);
    }
    int im[2];
    #pragma unroll
    for (int ib = 0; ib < 2; ib++)
        im[ib] = mask[n * Ln + it * 64 + ch * 32 + ib * 16 + m];

    float lacc[2] = {0.f, 0.f};
    floatx4 Oacc[2][4];
    #pragma unroll
    for (int ib = 0; ib < 2; ib++)
        #pragma unroll
        for (int at = 0; at < 4; at++) Oacc[ib][at] = (floatx4){0.f, 0.f, 0.f, 0.f};

    size_t hoff = (size_t)(n * Hn + h);

    issue_tiles(U + hoff * Ln * Dn, Ut + hoff * Dn * Ln, Ln, Us[0], Ub[0], w, l);
    if (t < 64) jms[0][t] = mask[n * Ln + t];
    __syncthreads();

    for (int jt = 0; jt < 17; jt++) {
        int cur = jt & 1, nxt = cur ^ 1;
        if (jt + 1 < 17) {
            const f16 *us, *ub; int sb;
            if (jt + 1 < 16) {
                us = U + (hoff * Ln + (size_t)(jt + 1) * 64) * Dn;
                ub = Ut + hoff * Dn * Ln + (jt + 1) * 64;
                sb = Ln;
            } else {
                us = GpA + (size_t)h * Gn * Dn;
                ub = Gpt + (size_t)h * Dn * Gn;
                sb = Gn;
            }
            issue_tiles(us, ub, sb, Us[nxt], Ub[nxt], w, l);
            if (t < 64) jms[nxt][t] = (jt + 1 < 16) ? mask[n * Ln + (jt + 1) * 64 + t] : 1;
        }
        int isg = (jt == 16);
        #pragma unroll
        for (int jb = 0; jb < 2; jb++) {
            int r0 = rh * 32 + jb * 16 + m;
            half8 au[4];
            #pragma unroll
            for (int ks = 0; ks < 4; ks++)
                au[ks] = *(const half8*)&Us[cur][((size_t)r0 << 7) + ((((ks << 2) + q)) ^ (r0 & 7)) * 8];
            int jmr[4];
            #pragma unroll
            for (int reg = 0; reg < 4; reg++)
                jmr[reg] = jms[cur][rh * 32 + jb * 16 + 4 * q + reg];
            #pragma unroll
            for (int ib = 0; ib < 2; ib++) {
                floatx4 s = {0.f, 0.f, 0.f, 0.f};
                #pragma unroll
                for (int ks = 0; ks < 4; ks++) s = MFMA(au[ks], bq[ib][ks], s);
                half4v pk;
                #pragma unroll
                for (int reg = 0; reg < 4; reg++) {
                    float p = (isg || (im[ib] && jmr[reg])) ? __expf(fminf(s[reg], 11.f)) : 0.f;
                    lacc[ib] += p;
                    pk[reg] = (f16)p;
                }
                *(half4v*)&Ps[(ch * 32 + ib * 16 + m) * PPAD + rh * 32 + jb * 16 + 4 * q] = pk;
            }
        }
        __syncthreads();

        #pragma unroll
        for (int kst = 0; kst < 2; kst++) {
            half8 aP[2];
            #pragma unroll
            for (int ib = 0; ib < 2; ib++)
                aP[ib] = *(const half8*)&Ps[(ih * 32 + ib * 16 + m) * PPAD + kst * 32 + q * 8];
            #pragma unroll
            for (int at = 0; at < 4; at++) {
                int r0 = ah * 64 + at * 16 + m;
                half8 bU = *(const half8*)&Ub[cur][((size_t)r0 << 6) + ((((kst << 2) + q)) ^ (r0 & 7)) * 8];
                #pragma unroll
                for (int ib = 0; ib < 2; ib++)
                    Oacc[ib][at] = MFMA(aP[ib], bU, Oacc[ib][at]);
            }
        }
        __syncthreads();
    }

    #pragma unroll
    for (int ib = 0; ib < 2; ib++) {
        float v = lacc[ib];
        v += __shfl_xor(v, 16, 64);
        v += __shfl_xor(v, 32, 64);
        lacc[ib] = v;
    }
    if (q == 0) {
        lpart[rh][ch * 32 + m] = lacc[0];
        lpart[rh][ch * 32 + 16 + m] = lacc[1];
    }
    __syncthreads();
    size_t rbase = hoff * Ln + (size_t)it * 64;
    if (t < 64) {
        float inv = 1.0f / (lpart[0][t] + lpart[1][t]);
        linvS[t] = inv;
        int mk = mask[n * Ln + it * 64 + t];
        rowLinv[rbase + t] = mk ? inv : 0.f;
    }
    __syncthreads();
    f16* Mo = Macc + rbase * Dn;
    #pragma unroll
    for (int ib = 0; ib < 2; ib++)
        #pragma unroll
        for (int reg = 0; reg < 4; reg++) {
            int row = ih * 32 + ib * 16 + 4 * q + reg;
            float inv = linvS[row];
            #pragma unroll
            for (int at = 0; at < 4; at++)
                Mo[(size_t)row * Dn + ah * 64 + at * 16 + m] = (f16)(Oacc[ib][at][reg] * inv);
        }
}

// ---------------- msg_j: R7-exact (DMA double-buffer) -----------------------
__launch_bounds__(256, 2)
__global__ void msgj_kernel(const f16* __restrict__ Qz, const f16* __restrict__ U,
                            const f16* __restrict__ Vt, const int* __restrict__ mask,
                            const float* __restrict__ rowLinv, f16* __restrict__ Macc) {
    int jt = blockIdx.x, h = blockIdx.y, n = blockIdx.z;
    int t = threadIdx.x;
    int w = t >> 6, l = t & 63, m = l & 15, q = l >> 4;
    int ihs = w >> 1, jhs = w & 1;
    int jh2 = w >> 1, bh = w & 1;

    __shared__ __align__(16) f16 Qs[2][64 * 128];
    __shared__ __align__(16) f16 Vb[2][128 * 64];
    __shared__ __align__(16) f16 Psj[64 * PPAD];
    __shared__ float lvS[2][64];

    size_t hoff = (size_t)(n * Hn + h);

    half8 bu[2][4];
    #pragma unroll
    for (int jb = 0; jb < 2; jb++) {
        const f16* ur = U + (hoff * Ln + (size_t)jt * 64 + jhs * 32 + jb * 16 + m) * Dn;
        #pragma unroll
        for (int ks = 0; ks < 4; ks++)
            bu[jb][ks] = *(const half8*)(ur + ks * 32 + q * 8);
    }
    int jm[2];
    #pragma unroll
    for (int jb = 0; jb < 2; jb++)
        jm[jb] = mask[n * Ln + jt * 64 + jhs * 32 + jb * 16 + m];

    floatx4 Oacc[2][4];
    #pragma unroll
    for (int jb = 0; jb < 2; jb++)
        #pragma unroll
        for (int bt = 0; bt < 4; bt++) Oacc[jb][bt] = (floatx4){0.f, 0.f, 0.f, 0.f};

    issue_tiles(Qz + (size_t)n * Ln * Dn, Vt + hoff * Dn * Ln, Ln, Qs[0], Vb[0], w, l);
    if (t < 64) lvS[0][t] = rowLinv[hoff * Ln + t];
    __syncthreads();

    for (int it2 = 0; it2 < 16; it2++) {
        int cur = it2 & 1, nxt = cur ^ 1;
        if (it2 + 1 < 16) {
            issue_tiles(Qz + ((size_t)n * Ln + (size_t)(it2 + 1) * 64) * Dn,
                        Vt + hoff * Dn * Ln + (it2 + 1) * 64, Ln, Qs[nxt], Vb[nxt], w, l);
            if (t < 64) lvS[nxt][t] = rowLinv[hoff * Ln + (it2 + 1) * 64 + t];
        }
        #pragma unroll
        for (int ib = 0; ib < 2; ib++) {
            int r0 = ihs * 32 + ib * 16 + m;
            half8 aq2[4];
            #pragma unroll
            for (int ks = 0; ks < 4; ks++)
                aq2[ks] = *(const half8*)&Qs[cur][((size_t)r0 << 7) + ((((ks << 2) + q)) ^ (r0 & 7)) * 8];
            float lv[4];
            #pragma unroll
            for (int reg = 0; reg < 4; reg++)
                lv[reg] = lvS[cur][ihs * 32 + ib * 16 + 4 * q + reg];
            #pragma unroll
            for (int jb = 0; jb < 2; jb++) {
                floatx4 s = {0.f, 0.f, 0.f, 0.f};
                #pragma unroll
                for (int ks = 0; ks < 4; ks++) s = MFMA(aq2[ks], bu[jb][ks], s);
                half4v pk;
                #pragma unroll
                for (int reg = 0; reg < 4; reg++) {
                    float p = jm[jb] ? __expf(fminf(s[reg], 11.f)) * lv[reg] : 0.f;
                    pk[reg] = (f16)p;
                }
                *(half4v*)&Psj[(jhs * 32 + jb * 16 + m) * PPAD + ihs * 32 + ib * 16 + 4 * q] = pk;
            }
        }
        __syncthreads();

        #pragma unroll
        for (int kst = 0; kst < 2; kst++) {
            half8 aP[2];
            #pragma unroll
            for (int jb = 0; jb < 2; jb++)
                aP[jb] = *(const half8*)&Psj[(jh2 * 32 + jb * 16 + m) * PPAD + kst * 32 + q * 8];
            #pragma unroll
            for (int bt = 0; bt < 4; bt++) {
                int r0 = bh * 64 + bt * 16 + m;
                half8 bV = *(const half8*)&Vb[cur][((size_t)r0 << 6) + ((((kst << 2) + q)) ^ (r0 & 7)) * 8];
                #pragma unroll
                for (int jb = 0; jb < 2; jb++)
                    Oacc[jb][bt] = MFMA(aP[jb], bV, Oacc[jb][bt]);
            }
        }
        __syncthreads();
    }

    f16* Mo = Macc + (hoff * Ln + (size_t)jt * 64) * Dn;
    #pragma unroll
    for (int jb = 0; jb < 2; jb++)
        #pragma unroll
        for (int reg = 0; reg < 4; reg++) {
            int row = jh2 * 32 + jb * 16 + 4 * q + reg;
            #pragma unroll
            for (int bt = 0; bt < 4; bt++) {
                f16* p = &Mo[(size_t)row * Dn + bh * 64 + bt * 16 + m];
                *p = (f16)((float)*p + Oacc[jb][bt][reg]);
            }
        }
}

// ---------------- fused combine (+softmax | +mask), 2 rows per block --------
__global__ void combine_kernel(const float* __restrict__ x, const f16* __restrict__ Macc,
                               const int* __restrict__ mask, float* __restrict__ out,
                               f16* __restrict__ Qzh, int do_softmax, int do_mask) {
    int t = threadIdx.x;            // 0..255
    int half = t >> 7;              // which of the 2 rows
    int t2 = t & 127;
    int row = blockIdx.x * 2 + half;
    __shared__ float red[4];
    int n = row >> 10;
    float acc = x[(size_t)row * Dn + t2];
    const f16* mp = Macc + (size_t)n * Hn * Ln * Dn + (size_t)(row & 1023) * Dn + t2;
    #pragma unroll
    for (int h = 0; h < Hn; h++) acc += (float)mp[(size_t)h * Ln * Dn];
    float o = acc;
    if (do_mask && mask[row] == 0) o = 0.f;
    out[(size_t)row * Dn + t2] = o;
    if (do_softmax) {
        float m = acc;
        #pragma unroll
        for (int off = 1; off < 64; off <<= 1) m = fmaxf(m, __shfl_xor(m, off, 64));
        if ((t & 63) == 0) red[t >> 6] = m;
        __syncthreads();
        m = fmaxf(red[2 * half], red[2 * half + 1]);
        float e = __expf(acc - m);
        float s = e;
        #pragma unroll
        for (int off = 1; off < 64; off <<= 1) s += __shfl_xor(s, off, 64);
        __syncthreads();
        if ((t & 63) == 0) red[t >> 6] = s;
        __syncthreads();
        s = red[2 * half] + red[2 * half + 1];
        Qzh[(size_t)row * Dn + t2] = (f16)(e / s);
    }
}

extern "C" void kernel_launch(void* const* d_in, const int* in_sizes, int n_in,
                              void* d_out, int out_size, void* d_ws, size_t ws_size,
                              hipStream_t stream) {
    const float* x       = (const float*)d_in[0];
    const int*   mask    = (const int*)d_in[1];
    const float* ternary = (const float*)d_in[2];
    const float* global_ = (const float*)d_in[3];
    float* out = (float*)d_out;
    (void)ws_size; (void)n_in; (void)in_sizes; (void)out_size;

    char* ws = (char*)d_ws;
    size_t o = 0;
    f16* Qzh = (f16*)(ws + o); o += (size_t)Bn * Ln * Dn * 2;
    f16* U   = (f16*)(ws + o); o += (size_t)Bn * Hn * Ln * Dn * 2;
    f16* Ut  = (f16*)(ws + o); o += (size_t)Bn * Hn * Ln * Dn * 2;
    f16* Vt  = (f16*)(ws + o); o += (size_t)Bn * Hn * Ln * Dn * 2;
    f16* TpA = (f16*)(ws + o); o += (size_t)Hn * Dn * Dn * 2;
    f16* TpB = (f16*)(ws + o); o += (size_t)Hn * Dn * Dn * 2;
    f16* GpA = (f16*)(ws + o); o += (size_t)Hn * Gn * Dn * 2;
    f16* Gpt = (f16*)(ws + o); o += (size_t)Hn * Dn * Gn * 2;
    float* rowLinv = (float*)(ws + o); o += (size_t)Bn * Hn * Ln * 4;
    f16* Macc = (f16*)(ws + o); o += (size_t)Bn * Hn * Ln * Dn * 2;

    repack_kernel<<<(Dn * Dn * Hn + 255) / 256, 256, 0, stream>>>(ternary, global_, TpA, TpB, GpA, Gpt);
    softmax_rows_kernel<<<Bn * Ln, 128, 0, stream>>>(x, Qzh);

    for (int it = 0; it < NITERS; it++) {
        uv_kernel<<<dim3(Ln / 64, Hn, Bn), 256, 0, stream>>>(Qzh, TpA, TpB, U, Ut, Vt);
        msgi_kernel<<<dim3(Ln / 64, Hn, Bn), 256, 0, stream>>>(Qzh, U, Ut, GpA, Gpt, mask, Macc, rowLinv);
        msgj_kernel<<<dim3(Ln / 64, Hn, Bn), 256, 0, stream>>>(Qzh, U, Vt, mask, rowLinv, Macc);
        combine_kernel<<<Bn * Ln / 2, 256, 0, stream>>>(x, Macc, mask, out, Qzh,
                                                        (it < NITERS - 1) ? 1 : 0,
                                                        (it == NITERS - 1) ? 1 : 0);
    }
}

// Round 10
// 400.581 us; speedup vs baseline: 1.4978x; 1.1556x over previous
//
#include <hip/hip_runtime.h>
#include <math.h>

#define Bn 4
#define Ln 1024
#define Dn 128
#define Hn 8
#define Gn 64
#define NITERS 4

typedef _Float16 f16;
typedef _Float16 half8 __attribute__((ext_vector_type(8)));
typedef _Float16 half4v __attribute__((ext_vector_type(4)));
typedef float floatx4 __attribute__((ext_vector_type(4)));

#define WPAD 136   // f16 stride for uv_kernel row-major T tiles
#define PPAD 72    // f16 stride, P tile [i][j] / [j][i]

#define MFMA(a, b, c) __builtin_amdgcn_mfma_f32_16x16x32_f16((a), (b), (c), 0, 0, 0)

// async global->LDS, 16B per lane; dest = lds_base + lane*16 (wave-uniform base)
__device__ __forceinline__ void gl_lds16(const f16* g, f16* l) {
    __builtin_amdgcn_global_load_lds(
        (const __attribute__((address_space(1))) void*)(g),
        (__attribute__((address_space(3))) void*)(l),
        16, 0, 0);
}

// Issue one 64x128 tile (row stride Dn) into UsB and one 128x64 tile (row
// stride sb) into UbB, both XOR-swizzled: 16B-group g stored at g^(row&7).
__device__ __forceinline__ void issue_tiles(const f16* us, const f16* ub, int sb,
                                            f16* UsB, f16* UbB, int w, int l) {
    #pragma unroll
    for (int k = 0; k < 4; k++) {
        int c = w * 4 + k;
        {   // Us: 64 rows x 16 groups
            int r = c * 4 + (l >> 4); int g = (l & 15) ^ (r & 7);
            gl_lds16(us + (size_t)r * Dn + g * 8, UsB + c * 512);
        }
        {   // Ub: 128 rows x 8 groups
            int r = c * 8 + (l >> 3); int g = (l & 7) ^ (r & 7);
            gl_lds16(ub + (size_t)r * sb + g * 8, UbB + c * 512);
        }
    }
}

// ---------------- repack ternary/global into f16 per-head layouts -----------
__global__ void repack_kernel(const float* __restrict__ ter, const float* __restrict__ glb,
                              f16* __restrict__ TpA, f16* __restrict__ TpB,
                              f16* __restrict__ GpA, f16* __restrict__ Gpt) {
    int idx = blockIdx.x * 256 + threadIdx.x;
    if (idx < Dn * Dn * Hn) {
        int h = idx % Hn; int b = (idx / Hn) % Dn; int a = idx / (Hn * Dn);
        f16 v = (f16)ter[idx];
        TpA[((size_t)h * Dn + a) * Dn + b] = v;
        TpB[((size_t)h * Dn + b) * Dn + a] = v;
    }
    if (idx < Gn * Dn * Hn) {
        int h = idx % Hn; int a = (idx / Hn) % Dn; int g = idx / (Hn * Dn);
        f16 v = (f16)glb[idx];
        GpA[((size_t)h * Gn + g) * Dn + a] = v;
        Gpt[((size_t)h * Dn + a) * Gn + g] = v;
    }
}

// ---------------- row softmax over D=128 (fp32 in, f16 out) -----------------
__global__ void softmax_rows_kernel(const float* __restrict__ in, f16* __restrict__ out) {
    int row = blockIdx.x;
    int t = threadIdx.x;  // 0..127
    __shared__ float red[2];
    float v = in[(size_t)row * Dn + t];
    float m = v;
    #pragma unroll
    for (int off = 1; off < 64; off <<= 1) m = fmaxf(m, __shfl_xor(m, off, 64));
    if ((t & 63) == 0) red[t >> 6] = m;
    __syncthreads();
    m = fmaxf(red[0], red[1]);
    float e = __expf(v - m);
    float s = e;
    #pragma unroll
    for (int off = 1; off < 64; off <<= 1) s += __shfl_xor(s, off, 64);
    __syncthreads();
    if ((t & 63) == 0) red[t >> 6] = s;
    __syncthreads();
    s = red[0] + red[1];
    out[(size_t)row * Dn + t] = (f16)(e / s);
}

// ---------------- U/V projection: staged-LDS T + all-packed stores ----------
// Stage TpA -> pass 1 (Ut, packed) + pass 3 (U via operand role swap: A = T
// a-rows from LDS, B = resident Qz -> C lands a-consecutive, packed half4v).
// Barrier, stage TpB -> pass 2 (Vt, packed). Fragments always fed from LDS
// (direct-global fragment feeds measured 2x slower — R8/R9).
__launch_bounds__(256, 4)
__global__ void uv_kernel(const f16* __restrict__ Qz, const f16* __restrict__ TpA,
                          const f16* __restrict__ TpB,
                          f16* __restrict__ U, f16* __restrict__ Ut, f16* __restrict__ Vt) {
    int bx = blockIdx.x;  // 16 j-strips of 64
    int h  = blockIdx.y;
    int n  = blockIdx.z;
    int t  = threadIdx.x;
    int w = t >> 6, l = t & 63, m = l & 15, q = l >> 4;

    __shared__ __align__(16) f16 Ts[128 * WPAD];

    const f16* qbase = Qz + ((size_t)n * Ln + bx * 64 + w * 16 + m) * Dn;
    half8 aq[4];
    #pragma unroll
    for (int ks = 0; ks < 4; ks++)
        aq[ks] = *(const half8*)(qbase + ks * 32 + q * 8);

    size_t hoff = (size_t)(n * Hn + h);
    int jr0 = bx * 64 + w * 16 + 4 * q;

    // ---- stage TpA ----
    {
        const f16* src = TpA + (size_t)h * Dn * Dn;
        for (int ii = 0; ii < 8; ii++) {
            int idx = t + 256 * ii; int r = idx >> 4, c = idx & 15;
            *(float4*)&Ts[r * WPAD + c * 8] = *(const float4*)(src + (size_t)r * Dn + c * 8);
        }
        __syncthreads();
    }
    // ---- pass 1: Ut[a][j], packed j-direction stores ----
    #pragma unroll
    for (int ct = 0; ct < 8; ct++) {
        floatx4 acc = {0.f, 0.f, 0.f, 0.f};
        #pragma unroll
        for (int ks = 0; ks < 4; ks++) {
            half8 b = *(const half8*)&Ts[(ct * 16 + m) * WPAD + ks * 32 + q * 8];
            acc = MFMA(aq[ks], b, acc);
        }
        half4v pk = { (f16)acc[0], (f16)acc[1], (f16)acc[2], (f16)acc[3] };
        *(half4v*)(Ut + (hoff * Dn + ct * 16 + m) * Ln + jr0) = pk;
    }
    // ---- pass 3: U[j][a], role swap (A = T a-rows from LDS, B = aq) ----
    // C rows = a (at*16+4q+reg), cols = j (w*16+m) -> a-consecutive store
    f16* urow = U + (hoff * Ln + (size_t)(bx * 64 + w * 16 + m)) * Dn;
    #pragma unroll
    for (int at = 0; at < 8; at++) {
        floatx4 acc = {0.f, 0.f, 0.f, 0.f};
        #pragma unroll
        for (int ks = 0; ks < 4; ks++) {
            half8 aT = *(const half8*)&Ts[(at * 16 + m) * WPAD + ks * 32 + q * 8];
            acc = MFMA(aT, aq[ks], acc);
        }
        half4v pk = { (f16)acc[0], (f16)acc[1], (f16)acc[2], (f16)acc[3] };
        *(half4v*)(urow + at * 16 + 4 * q) = pk;
    }
    __syncthreads();
    // ---- stage TpB ----
    {
        const f16* src = TpB + (size_t)h * Dn * Dn;
        for (int ii = 0; ii < 8; ii++) {
            int idx = t + 256 * ii; int r = idx >> 4, c = idx & 15;
            *(float4*)&Ts[r * WPAD + c * 8] = *(const float4*)(src + (size_t)r * Dn + c * 8);
        }
        __syncthreads();
    }
    // ---- pass 2: Vt[b][i], packed ----
    #pragma unroll
    for (int ct = 0; ct < 8; ct++) {
        floatx4 acc = {0.f, 0.f, 0.f, 0.f};
        #pragma unroll
        for (int ks = 0; ks < 4; ks++) {
            half8 b = *(const half8*)&Ts[(ct * 16 + m) * WPAD + ks * 32 + q * 8];
            acc = MFMA(aq[ks], b, acc);
        }
        half4v pk = { (f16)acc[0], (f16)acc[1], (f16)acc[2], (f16)acc[3] };
        *(half4v*)(Vt + (hoff * Dn + ct * 16 + m) * Ln + jr0) = pk;
    }
}

// ---------------- msg_i + msg_g: R7-exact (DMA double-buffer) ---------------
__launch_bounds__(256, 2)
__global__ void msgi_kernel(const f16* __restrict__ Qz, const f16* __restrict__ U,
                            const f16* __restrict__ Ut, const f16* __restrict__ GpA,
                            const f16* __restrict__ Gpt, const int* __restrict__ mask,
                            f16* __restrict__ Macc, float* __restrict__ rowLinv) {
    int it = blockIdx.x, h = blockIdx.y, n = blockIdx.z;
    int t = threadIdx.x;
    int w = t >> 6, l = t & 63, m = l & 15, q = l >> 4;
    int rh = w >> 1, ch = w & 1;   // scores: j-half (rows), i-half (cols)
    int ih = w >> 1, ah = w & 1;   // PV: i-half (rows), a-half (cols)

    __shared__ __align__(16) f16 Us[2][64 * 128];    // U j-tile, swizzled
    __shared__ __align__(16) f16 Ub[2][128 * 64];    // Ut slice [a][j], swizzled
    __shared__ __align__(16) f16 Ps[64 * PPAD];      // P[i][j], padded
    __shared__ int jms[2][64];
    __shared__ float lpart[2][64];
    __shared__ float linvS[64];

    half8 bq[2][4];
    #pragma unroll
    for (int ib = 0; ib < 2; ib++) {
        const f16* qr = Qz + ((size_t)n * Ln + it * 64 + ch * 32 + ib * 16 + m) * Dn;
        #pragma unroll
        for (int ks = 0; ks < 4; ks++)
            bq[ib][ks] = *(const half8*)(qr + ks * 32 + q * 8);
    }
    int im[2];
    #pragma unroll
    for (int ib = 0; ib < 2; ib++)
        im[ib] = mask[n * Ln + it * 64 + ch * 32 + ib * 16 + m];

    float lacc[2] = {0.f, 0.f};
    floatx4 Oacc[2][4];
    #pragma unroll
    for (int ib = 0; ib < 2; ib++)
        #pragma unroll
        for (int at = 0; at < 4; at++) Oacc[ib][at] = (floatx4){0.f, 0.f, 0.f, 0.f};

    size_t hoff = (size_t)(n * Hn + h);

    issue_tiles(U + hoff * Ln * Dn, Ut + hoff * Dn * Ln, Ln, Us[0], Ub[0], w, l);
    if (t < 64) jms[0][t] = mask[n * Ln + t];
    __syncthreads();

    for (int jt = 0; jt < 17; jt++) {
        int cur = jt & 1, nxt = cur ^ 1;
        if (jt + 1 < 17) {
            const f16 *us, *ub; int sb;
            if (jt + 1 < 16) {
                us = U + (hoff * Ln + (size_t)(jt + 1) * 64) * Dn;
                ub = Ut + hoff * Dn * Ln + (jt + 1) * 64;
                sb = Ln;
            } else {
                us = GpA + (size_t)h * Gn * Dn;
                ub = Gpt + (size_t)h * Dn * Gn;
                sb = Gn;
            }
            issue_tiles(us, ub, sb, Us[nxt], Ub[nxt], w, l);
            if (t < 64) jms[nxt][t] = (jt + 1 < 16) ? mask[n * Ln + (jt + 1) * 64 + t] : 1;
        }
        int isg = (jt == 16);
        #pragma unroll
        for (int jb = 0; jb < 2; jb++) {
            int r0 = rh * 32 + jb * 16 + m;
            half8 au[4];
            #pragma unroll
            for (int ks = 0; ks < 4; ks++)
                au[ks] = *(const half8*)&Us[cur][((size_t)r0 << 7) + ((((ks << 2) + q)) ^ (r0 & 7)) * 8];
            int jmr[4];
            #pragma unroll
            for (int reg = 0; reg < 4; reg++)
                jmr[reg] = jms[cur][rh * 32 + jb * 16 + 4 * q + reg];
            #pragma unroll
            for (int ib = 0; ib < 2; ib++) {
                floatx4 s = {0.f, 0.f, 0.f, 0.f};
                #pragma unroll
                for (int ks = 0; ks < 4; ks++) s = MFMA(au[ks], bq[ib][ks], s);
                half4v pk;
                #pragma unroll
                for (int reg = 0; reg < 4; reg++) {
                    float p = (isg || (im[ib] && jmr[reg])) ? __expf(fminf(s[reg], 11.f)) : 0.f;
                    lacc[ib] += p;
                    pk[reg] = (f16)p;
                }
                *(half4v*)&Ps[(ch * 32 + ib * 16 + m) * PPAD + rh * 32 + jb * 16 + 4 * q] = pk;
            }
        }
        __syncthreads();

        #pragma unroll
        for (int kst = 0; kst < 2; kst++) {
            half8 aP[2];
            #pragma unroll
            for (int ib = 0; ib < 2; ib++)
                aP[ib] = *(const half8*)&Ps[(ih * 32 + ib * 16 + m) * PPAD + kst * 32 + q * 8];
            #pragma unroll
            for (int at = 0; at < 4; at++) {
                int r0 = ah * 64 + at * 16 + m;
                half8 bU = *(const half8*)&Ub[cur][((size_t)r0 << 6) + ((((kst << 2) + q)) ^ (r0 & 7)) * 8];
                #pragma unroll
                for (int ib = 0; ib < 2; ib++)
                    Oacc[ib][at] = MFMA(aP[ib], bU, Oacc[ib][at]);
            }
        }
        __syncthreads();
    }

    #pragma unroll
    for (int ib = 0; ib < 2; ib++) {
        float v = lacc[ib];
        v += __shfl_xor(v, 16, 64);
        v += __shfl_xor(v, 32, 64);
        lacc[ib] = v;
    }
    if (q == 0) {
        lpart[rh][ch * 32 + m] = lacc[0];
        lpart[rh][ch * 32 + 16 + m] = lacc[1];
    }
    __syncthreads();
    size_t rbase = hoff * Ln + (size_t)it * 64;
    if (t < 64) {
        float inv = 1.0f / (lpart[0][t] + lpart[1][t]);
        linvS[t] = inv;
        int mk = mask[n * Ln + it * 64 + t];
        rowLinv[rbase + t] = mk ? inv : 0.f;
    }
    __syncthreads();
    f16* Mo = Macc + rbase * Dn;
    #pragma unroll
    for (int ib = 0; ib < 2; ib++)
        #pragma unroll
        for (int reg = 0; reg < 4; reg++) {
            int row = ih * 32 + ib * 16 + 4 * q + reg;
            float inv = linvS[row];
            #pragma unroll
            for (int at = 0; at < 4; at++)
                Mo[(size_t)row * Dn + ah * 64 + at * 16 + m] = (f16)(Oacc[ib][at][reg] * inv);
        }
}

// ---------------- msg_j: R7-exact (DMA double-buffer) -----------------------
__launch_bounds__(256, 2)
__global__ void msgj_kernel(const f16* __restrict__ Qz, const f16* __restrict__ U,
                            const f16* __restrict__ Vt, const int* __restrict__ mask,
                            const float* __restrict__ rowLinv, f16* __restrict__ Macc) {
    int jt = blockIdx.x, h = blockIdx.y, n = blockIdx.z;
    int t = threadIdx.x;
    int w = t >> 6, l = t & 63, m = l & 15, q = l >> 4;
    int ihs = w >> 1, jhs = w & 1;
    int jh2 = w >> 1, bh = w & 1;

    __shared__ __align__(16) f16 Qs[2][64 * 128];
    __shared__ __align__(16) f16 Vb[2][128 * 64];
    __shared__ __align__(16) f16 Psj[64 * PPAD];
    __shared__ float lvS[2][64];

    size_t hoff = (size_t)(n * Hn + h);

    half8 bu[2][4];
    #pragma unroll
    for (int jb = 0; jb < 2; jb++) {
        const f16* ur = U + (hoff * Ln + (size_t)jt * 64 + jhs * 32 + jb * 16 + m) * Dn;
        #pragma unroll
        for (int ks = 0; ks < 4; ks++)
            bu[jb][ks] = *(const half8*)(ur + ks * 32 + q * 8);
    }
    int jm[2];
    #pragma unroll
    for (int jb = 0; jb < 2; jb++)
        jm[jb] = mask[n * Ln + jt * 64 + jhs * 32 + jb * 16 + m];

    floatx4 Oacc[2][4];
    #pragma unroll
    for (int jb = 0; jb < 2; jb++)
        #pragma unroll
        for (int bt = 0; bt < 4; bt++) Oacc[jb][bt] = (floatx4){0.f, 0.f, 0.f, 0.f};

    issue_tiles(Qz + (size_t)n * Ln * Dn, Vt + hoff * Dn * Ln, Ln, Qs[0], Vb[0], w, l);
    if (t < 64) lvS[0][t] = rowLinv[hoff * Ln + t];
    __syncthreads();

    for (int it2 = 0; it2 < 16; it2++) {
        int cur = it2 & 1, nxt = cur ^ 1;
        if (it2 + 1 < 16) {
            issue_tiles(Qz + ((size_t)n * Ln + (size_t)(it2 + 1) * 64) * Dn,
                        Vt + hoff * Dn * Ln + (it2 + 1) * 64, Ln, Qs[nxt], Vb[nxt], w, l);
            if (t < 64) lvS[nxt][t] = rowLinv[hoff * Ln + (it2 + 1) * 64 + t];
        }
        #pragma unroll
        for (int ib = 0; ib < 2; ib++) {
            int r0 = ihs * 32 + ib * 16 + m;
            half8 aq2[4];
            #pragma unroll
            for (int ks = 0; ks < 4; ks++)
                aq2[ks] = *(const half8*)&Qs[cur][((size_t)r0 << 7) + ((((ks << 2) + q)) ^ (r0 & 7)) * 8];
            float lv[4];
            #pragma unroll
            for (int reg = 0; reg < 4; reg++)
                lv[reg] = lvS[cur][ihs * 32 + ib * 16 + 4 * q + reg];
            #pragma unroll
            for (int jb = 0; jb < 2; jb++) {
                floatx4 s = {0.f, 0.f, 0.f, 0.f};
                #pragma unroll
                for (int ks = 0; ks < 4; ks++) s = MFMA(aq2[ks], bu[jb][ks], s);
                half4v pk;
                #pragma unroll
                for (int reg = 0; reg < 4; reg++) {
                    float p = jm[jb] ? __expf(fminf(s[reg], 11.f)) * lv[reg] : 0.f;
                    pk[reg] = (f16)p;
                }
                *(half4v*)&Psj[(jhs * 32 + jb * 16 + m) * PPAD + ihs * 32 + ib * 16 + 4 * q] = pk;
            }
        }
        __syncthreads();

        #pragma unroll
        for (int kst = 0; kst < 2; kst++) {
            half8 aP[2];
            #pragma unroll
            for (int jb = 0; jb < 2; jb++)
                aP[jb] = *(const half8*)&Psj[(jh2 * 32 + jb * 16 + m) * PPAD + kst * 32 + q * 8];
            #pragma unroll
            for (int bt = 0; bt < 4; bt++) {
                int r0 = bh * 64 + bt * 16 + m;
                half8 bV = *(const half8*)&Vb[cur][((size_t)r0 << 6) + ((((kst << 2) + q)) ^ (r0 & 7)) * 8];
                #pragma unroll
                for (int jb = 0; jb < 2; jb++)
                    Oacc[jb][bt] = MFMA(aP[jb], bV, Oacc[jb][bt]);
            }
        }
        __syncthreads();
    }

    f16* Mo = Macc + (hoff * Ln + (size_t)jt * 64) * Dn;
    #pragma unroll
    for (int jb = 0; jb < 2; jb++)
        #pragma unroll
        for (int reg = 0; reg < 4; reg++) {
            int row = jh2 * 32 + jb * 16 + 4 * q + reg;
            #pragma unroll
            for (int bt = 0; bt < 4; bt++) {
                f16* p = &Mo[(size_t)row * Dn + bh * 64 + bt * 16 + m];
                *p = (f16)((float)*p + Oacc[jb][bt][reg]);
            }
        }
}

// ---------------- fused combine (+softmax | +mask), 2 rows per block --------
__global__ void combine_kernel(const float* __restrict__ x, const f16* __restrict__ Macc,
                               const int* __restrict__ mask, float* __restrict__ out,
                               f16* __restrict__ Qzh, int do_softmax, int do_mask) {
    int t = threadIdx.x;            // 0..255
    int half = t >> 7;              // which of the 2 rows
    int t2 = t & 127;
    int row = blockIdx.x * 2 + half;
    __shared__ float red[4];
    int n = row >> 10;
    float acc = x[(size_t)row * Dn + t2];
    const f16* mp = Macc + (size_t)n * Hn * Ln * Dn + (size_t)(row & 1023) * Dn + t2;
    #pragma unroll
    for (int h = 0; h < Hn; h++) acc += (float)mp[(size_t)h * Ln * Dn];
    float o = acc;
    if (do_mask && mask[row] == 0) o = 0.f;
    out[(size_t)row * Dn + t2] = o;
    if (do_softmax) {
        float m = acc;
        #pragma unroll
        for (int off = 1; off < 64; off <<= 1) m = fmaxf(m, __shfl_xor(m, off, 64));
        if ((t & 63) == 0) red[t >> 6] = m;
        __syncthreads();
        m = fmaxf(red[2 * half], red[2 * half + 1]);
        float e = __expf(acc - m);
        float s = e;
        #pragma unroll
        for (int off = 1; off < 64; off <<= 1) s += __shfl_xor(s, off, 64);
        __syncthreads();
        if ((t & 63) == 0) red[t >> 6] = s;
        __syncthreads();
        s = red[2 * half] + red[2 * half + 1];
        Qzh[(size_t)row * Dn + t2] = (f16)(e / s);
    }
}

extern "C" void kernel_launch(void* const* d_in, const int* in_sizes, int n_in,
                              void* d_out, int out_size, void* d_ws, size_t ws_size,
                              hipStream_t stream) {
    const float* x       = (const float*)d_in[0];
    const int*   mask    = (const int*)d_in[1];
    const float* ternary = (const float*)d_in[2];
    const float* global_ = (const float*)d_in[3];
    float* out = (float*)d_out;
    (void)ws_size; (void)n_in; (void)in_sizes; (void)out_size;

    char* ws = (char*)d_ws;
    size_t o = 0;
    f16* Qzh = (f16*)(ws + o); o += (size_t)Bn * Ln * Dn * 2;
    f16* U   = (f16*)(ws + o); o += (size_t)Bn * Hn * Ln * Dn * 2;
    f16* Ut  = (f16*)(ws + o); o += (size_t)Bn * Hn * Ln * Dn * 2;
    f16* Vt  = (f16*)(ws + o); o += (size_t)Bn * Hn * Ln * Dn * 2;
    f16* TpA = (f16*)(ws + o); o += (size_t)Hn * Dn * Dn * 2;
    f16* TpB = (f16*)(ws + o); o += (size_t)Hn * Dn * Dn * 2;
    f16* GpA = (f16*)(ws + o); o += (size_t)Hn * Gn * Dn * 2;
    f16* Gpt = (f16*)(ws + o); o += (size_t)Hn * Dn * Gn * 2;
    float* rowLinv = (float*)(ws + o); o += (size_t)Bn * Hn * Ln * 4;
    f16* Macc = (f16*)(ws + o); o += (size_t)Bn * Hn * Ln * Dn * 2;

    repack_kernel<<<(Dn * Dn * Hn + 255) / 256, 256, 0, stream>>>(ternary, global_, TpA, TpB, GpA, Gpt);
    softmax_rows_kernel<<<Bn * Ln, 128, 0, stream>>>(x, Qzh);

    for (int it = 0; it < NITERS; it++) {
        uv_kernel<<<dim3(Ln / 64, Hn, Bn), 256, 0, stream>>>(Qzh, TpA, TpB, U, Ut, Vt);
        msgi_kernel<<<dim3(Ln / 64, Hn, Bn), 256, 0, stream>>>(Qzh, U, Ut, GpA, Gpt, mask, Macc, rowLinv);
        msgj_kernel<<<dim3(Ln / 64, Hn, Bn), 256, 0, stream>>>(Qzh, U, Vt, mask, rowLinv, Macc);
        combine_kernel<<<Bn * Ln / 2, 256, 0, stream>>>(x, Macc, mask, out, Qzh,
                                                        (it < NITERS - 1) ? 1 : 0,
                                                        (it == NITERS - 1) ? 1 : 0);
    }
}